// Round 1
// baseline (64.173 us; speedup 1.0000x reference)
//
#include <hip/hip_runtime.h>

#define HH 1024
#define WW 1024
#define BS 16
#define TILE_W 256
#define ROWS 64
#define NPIX ((size_t)HH * (size_t)WW)

__device__ __forceinline__ float ldx(const float* __restrict__ xin, int row, int col) {
    if (row < 0 || row >= HH || col < 0 || col >= WW) return 0.0f;
    return xin[(size_t)row * WW + col];
}

__global__ __launch_bounds__(TILE_W) void nms_head_kernel(
    const float* __restrict__ in,      // (bs,1,H,W)
    const float* __restrict__ scale,   // (bs,)
    const float* __restrict__ center,  // (bs,2)
    float* __restrict__ out)           // masked_world (bs,2,H,W) ++ mask (bs,H,W)
{
    const int tid = threadIdx.x;
    const int c0 = blockIdx.x * TILE_W;
    const int r0 = blockIdx.y * ROWS;
    const int b  = blockIdx.z;

    const float s  = scale[b];
    const float cx = center[2 * b];
    const float cy = center[2 * b + 1];

    const float* xin = in + (size_t)b * NPIX;
    float* out_wx = out + (size_t)b * 2 * NPIX;
    float* out_wy = out_wx + NPIX;
    float* out_m  = out + (size_t)BS * 2 * NPIX + (size_t)b * NPIX;

    const int col = c0 + tid;

    // Halo columns: lanes 0,1 -> c0-2, c0-1 ; lanes 2,3 -> c0+256, c0+257
    const bool has_halo = (tid < 4);
    const int hcol = (tid < 2) ? (c0 - 2 + tid) : (c0 + TILE_W + (tid - 2));
    const int hidx = (tid < 2) ? tid : (TILE_W + tid);   // 0,1,258,259

    __shared__ float vrow[2][TILE_W + 4];

    // Vertical sliding window (rows y-2 .. y+2); zero padding matches the
    // reference's constant_values=0.0 pad (all inputs are >= 0).
    float va = ldx(xin, r0 - 2, col);
    float vb = ldx(xin, r0 - 1, col);
    float vc = ldx(xin, r0 + 0, col);
    float vd = ldx(xin, r0 + 1, col);
    float ha = 0.f, hb = 0.f, hc = 0.f, hd = 0.f;
    if (has_halo) {
        ha = ldx(xin, r0 - 2, hcol);
        hb = ldx(xin, r0 - 1, hcol);
        hc = ldx(xin, r0 + 0, hcol);
        hd = ldx(xin, r0 + 1, hcol);
    }

    const float wx = ((float)col - 0.5f * (float)WW) * s + cx;

    int p = 0;
    for (int y = r0; y < r0 + ROWS; ++y) {
        float ve = ldx(xin, y + 2, col);
        float vm = fmaxf(fmaxf(fmaxf(va, vb), fmaxf(vc, vd)), ve);
        vrow[p][tid + 2] = vm;
        if (has_halo) {
            float he = ldx(xin, y + 2, hcol);
            float hm = fmaxf(fmaxf(fmaxf(ha, hb), fmaxf(hc, hd)), he);
            vrow[p][hidx] = hm;
            ha = hb; hb = hc; hc = hd; hd = he;
        }
        __syncthreads();

        float h = fmaxf(fmaxf(fmaxf(vrow[p][tid],     vrow[p][tid + 1]),
                              fmaxf(vrow[p][tid + 2], vrow[p][tid + 3])),
                        vrow[p][tid + 4]);

        // center value of the 5x5 window is vc (row y, own column)
        const bool mk = (h > 1e-5f) && (h == vc);

        const float wy = (0.5f * (float)HH - (float)y) * s + cy;
        const size_t off = (size_t)y * WW + col;
        out_wx[off] = mk ? wx : 0.0f;
        out_wy[off] = mk ? wy : 0.0f;
        out_m[off]  = mk ? 1.0f : 0.0f;

        va = vb; vb = vc; vc = vd; vd = ve;
        p ^= 1;
    }
}

extern "C" void kernel_launch(void* const* d_in, const int* in_sizes, int n_in,
                              void* d_out, int out_size, void* d_ws, size_t ws_size,
                              hipStream_t stream) {
    const float* in     = (const float*)d_in[0];
    const float* scale  = (const float*)d_in[1];
    const float* center = (const float*)d_in[2];
    float* out = (float*)d_out;

    dim3 grid(WW / TILE_W, HH / ROWS, BS);
    nms_head_kernel<<<grid, dim3(TILE_W), 0, stream>>>(in, scale, center, out);
}

// Round 2
// 43.420 us; speedup vs baseline: 1.4780x; 1.4780x over previous
//
#include <hip/hip_runtime.h>

#define HH 1024
#define WW 1024
#define BS 16
#define ROWS 16
#define NPIX ((size_t)HH * (size_t)WW)

__device__ __forceinline__ float max5(float a, float b, float c, float d, float e) {
    return fmaxf(fmaxf(fmaxf(a, b), fmaxf(c, d)), e);
}

__device__ __forceinline__ float4 ldrow4(const float* __restrict__ x, int row, int col) {
    if ((unsigned)row < (unsigned)HH)
        return *reinterpret_cast<const float4*>(x + (size_t)row * WW + col);
    return make_float4(0.f, 0.f, 0.f, 0.f);
}

__device__ __forceinline__ float2 ldhalo2(const float* __restrict__ x, int row, int col) {
    if ((unsigned)row < (unsigned)HH && (unsigned)col < (unsigned)WW)
        return *reinterpret_cast<const float2*>(x + (size_t)row * WW + col);
    return make_float2(0.f, 0.f);
}

__global__ __launch_bounds__(256) void nms_head_kernel(
    const float* __restrict__ in,      // (bs,1,H,W)
    const float* __restrict__ scale,   // (bs,)
    const float* __restrict__ center,  // (bs,2)
    float* __restrict__ out)           // masked_world (bs,2,H,W) ++ mask (bs,H,W)
{
    const int tid  = threadIdx.x;
    const int lane = tid & 63;
    const int wv   = tid >> 6;          // wave id 0..3, each owns a 256-col strip
    const int c0   = wv * 256;
    const int col  = c0 + lane * 4;     // 4 consecutive columns per lane
    const int r0   = blockIdx.x * ROWS;
    const int b    = blockIdx.y;

    const float s  = scale[b];
    const float cx = center[2 * b];
    const float cy = center[2 * b + 1];

    const float* xin = in + (size_t)b * NPIX;
    float* out_wx = out + (size_t)b * 2 * NPIX;
    float* out_wy = out_wx + NPIX;
    float* out_m  = out + (size_t)BS * 2 * NPIX + (size_t)b * NPIX;

    // Wave-edge halo: lane 0 maintains cols c0-2,c0-1 ; lane 63 cols c0+256,c0+257
    const bool hA = (lane == 0);
    const bool hB = (lane == 63);
    const bool halo = hA || hB;
    const int hcol = hA ? (c0 - 2) : (c0 + 256);

    // Vertical 5-tap sliding windows (zero pad == reference constant_values=0,
    // valid since all inputs are >= 0)
    float4 va = ldrow4(xin, r0 - 2, col);
    float4 vb = ldrow4(xin, r0 - 1, col);
    float4 vc = ldrow4(xin, r0 + 0, col);
    float4 vd = ldrow4(xin, r0 + 1, col);
    float2 ga = make_float2(0.f, 0.f), gb = ga, gc = ga, gd = ga;
    if (halo) {
        ga = ldhalo2(xin, r0 - 2, hcol);
        gb = ldhalo2(xin, r0 - 1, hcol);
        gc = ldhalo2(xin, r0 + 0, hcol);
        gd = ldhalo2(xin, r0 + 1, hcol);
    }

    const float wxx = ((float)(col + 0) - 512.0f) * s + cx;
    const float wxy = ((float)(col + 1) - 512.0f) * s + cx;
    const float wxz = ((float)(col + 2) - 512.0f) * s + cx;
    const float wxw = ((float)(col + 3) - 512.0f) * s + cx;

    for (int y = r0; y < r0 + ROWS; ++y) {
        float4 ve = ldrow4(xin, y + 2, col);
        float2 ge = halo ? ldhalo2(xin, y + 2, hcol) : make_float2(0.f, 0.f);

        float4 vm;
        vm.x = max5(va.x, vb.x, vc.x, vd.x, ve.x);
        vm.y = max5(va.y, vb.y, vc.y, vd.y, ve.y);
        vm.z = max5(va.z, vb.z, vc.z, vd.z, ve.z);
        vm.w = max5(va.w, vb.w, vc.w, vd.w, ve.w);
        float gmx = max5(ga.x, gb.x, gc.x, gd.x, ge.x);
        float gmy = max5(ga.y, gb.y, gc.y, gd.y, ge.y);

        // Neighbor exchange: 2 cols from left lane, 2 from right lane
        float Lx = __shfl_up(vm.z, 1);
        float Ly = __shfl_up(vm.w, 1);
        float Rx = __shfl_down(vm.x, 1);
        float Ry = __shfl_down(vm.y, 1);
        if (hA) { Lx = gmx; Ly = gmy; }
        if (hB) { Rx = gmx; Ry = gmy; }

        float h0 = max5(Lx, Ly, vm.x, vm.y, vm.z);
        float h1 = max5(Ly, vm.x, vm.y, vm.z, vm.w);
        float h2 = max5(vm.x, vm.y, vm.z, vm.w, Rx);
        float h3 = max5(vm.y, vm.z, vm.w, Rx, Ry);

        const bool m0 = (h0 > 1e-5f) && (h0 == vc.x);
        const bool m1 = (h1 > 1e-5f) && (h1 == vc.y);
        const bool m2 = (h2 > 1e-5f) && (h2 == vc.z);
        const bool m3 = (h3 > 1e-5f) && (h3 == vc.w);

        const float wy = (512.0f - (float)y) * s + cy;
        const size_t off = (size_t)y * WW + col;

        float4 owx = make_float4(m0 ? wxx : 0.f, m1 ? wxy : 0.f,
                                 m2 ? wxz : 0.f, m3 ? wxw : 0.f);
        float4 owy = make_float4(m0 ? wy : 0.f, m1 ? wy : 0.f,
                                 m2 ? wy : 0.f, m3 ? wy : 0.f);
        float4 om  = make_float4(m0 ? 1.f : 0.f, m1 ? 1.f : 0.f,
                                 m2 ? 1.f : 0.f, m3 ? 1.f : 0.f);

        *reinterpret_cast<float4*>(out_wx + off) = owx;
        *reinterpret_cast<float4*>(out_wy + off) = owy;
        *reinterpret_cast<float4*>(out_m  + off) = om;

        va = vb; vb = vc; vc = vd; vd = ve;
        ga = gb; gb = gc; gc = gd; gd = ge;
    }
}

extern "C" void kernel_launch(void* const* d_in, const int* in_sizes, int n_in,
                              void* d_out, int out_size, void* d_ws, size_t ws_size,
                              hipStream_t stream) {
    const float* in     = (const float*)d_in[0];
    const float* scale  = (const float*)d_in[1];
    const float* center = (const float*)d_in[2];
    float* out = (float*)d_out;

    dim3 grid(HH / ROWS, BS);
    nms_head_kernel<<<grid, dim3(256), 0, stream>>>(in, scale, center, out);
}